// Round 4
// baseline (712.039 us; speedup 1.0000x reference)
//
#include <hip/hip_runtime.h>

#define NUM_TAGS 128
#define NUM_FEATS 500000
#define BB 64
#define TT 512
#define FF 8

#define SWT_BYTES 128000000ull                 // 500000*128*2 (bf16)
#define EM_BYTES  (64ull * 512 * 128 * 2)      // 8 MB bf16
#define NEED_FULL (SWT_BYTES + EM_BYTES)

typedef __attribute__((ext_vector_type(8))) short short8;
typedef __attribute__((ext_vector_type(4))) float float4v;

__device__ inline unsigned short f2bf(float f) {
  unsigned u = __float_as_uint(f);
  return (unsigned short)((u + 0x7fffu + ((u >> 16) & 1u)) >> 16);
}
__device__ inline float bf2f(unsigned short h) {
  return __uint_as_float(((unsigned)h) << 16);
}

// T1: transpose sw [128][500000] fp32 -> swT [500000][128] bf16.
// 32f x 128k tile; float4 global reads; pad-33 LDS; uint-packed bf16 writes.
__global__ __launch_bounds__(256) void transpose_kernel(
    const float* __restrict__ sw, unsigned short* __restrict__ swT) {
  __shared__ float tile[128][33];
  const int f0 = blockIdx.x * 32;
  const int t = threadIdx.x;
  const int c = t & 7, kr = t >> 3;
#pragma unroll
  for (int p = 0; p < 4; ++p) {
    int k = kr + 32 * p;
    float4 v = *(const float4*)&sw[(size_t)k * NUM_FEATS + f0 + 4 * c];
    tile[k][4 * c + 0] = v.x; tile[k][4 * c + 1] = v.y;
    tile[k][4 * c + 2] = v.z; tile[k][4 * c + 3] = v.w;
  }
  __syncthreads();
  const int l = t & 63, fr = t >> 6;
#pragma unroll
  for (int p = 0; p < 8; ++p) {
    int f = fr + 4 * p;
    unsigned lo = f2bf(tile[2 * l][f]);
    unsigned hi = f2bf(tile[2 * l + 1][f]);
    *(unsigned*)&swT[(size_t)(f0 + f) * NUM_TAGS + 2 * l] = lo | (hi << 16);
  }
}

// K1: one wave per token; lane loads uint (2 bf16) -> full 256B row per
// wave-instruction. exp folded; em stored bf16 packed.
__global__ __launch_bounds__(256) void gather_kernel(
    const int* __restrict__ feats, const unsigned short* __restrict__ swT,
    unsigned short* __restrict__ em) {
  const int w = threadIdx.x >> 6, lane = threadIdx.x & 63;
  const int token = blockIdx.x * 4 + w;
  const int* f = feats + token * FF;
  int fi[FF];
#pragma unroll
  for (int i = 0; i < FF; ++i) fi[i] = f[i];
  float s0 = 0.f, s1 = 0.f;
#pragma unroll
  for (int i = 0; i < FF; ++i) {
    unsigned u = *(const unsigned*)&swT[(size_t)fi[i] * NUM_TAGS + 2 * lane];
    s0 += __uint_as_float(u << 16);
    s1 += __uint_as_float(u & 0xFFFF0000u);
  }
  unsigned lo = f2bf(__expf(s0));
  unsigned hi = f2bf(__expf(s1));
  *(unsigned*)&em[(size_t)token * NUM_TAGS + 2 * lane] = lo | (hi << 16);
}

// K1b fallback: direct strided fp32 gather, bf16 out.
__global__ __launch_bounds__(256) void gather_f_kernel(
    const int* __restrict__ feats, const float* __restrict__ sw,
    unsigned short* __restrict__ em) {
  const int w = threadIdx.x >> 6, lane = threadIdx.x & 63;
  const int token = blockIdx.x * 4 + w;
  const int* f = feats + token * FF;
  float s0 = 0.f, s1 = 0.f;
#pragma unroll
  for (int i = 0; i < FF; ++i) {
    s0 += sw[(size_t)(2 * lane) * NUM_FEATS + f[i]];
    s1 += sw[(size_t)(2 * lane + 1) * NUM_FEATS + f[i]];
  }
  unsigned lo = f2bf(__expf(s0));
  unsigned hi = f2bf(__expf(s1));
  *(unsigned*)&em[(size_t)token * NUM_TAGS + 2 * lane] = lo | (hi << 16);
}

// K2: single-wave barrier-free MFMA forward. Wave 0: full 128x128 E as
// A-frags in 128 VGPRs; alpha in-place in LDS bf16 [16b][128j] (same-wave DS
// ordering => no s_barrier in the recurrence; no vmcnt(0) drain -> ev
// prefetch stays in flight). Wave 1: gold score concurrently. One barrier
// at the very end.
#define NB 16
#define LROW 136   // shorts; 272B rows: 16B-aligned for b128

__global__ __launch_bounds__(128, 1) void fwd_kernel(
    const unsigned short* __restrict__ em, const int* __restrict__ tags,
    const float* __restrict__ trans, const float* __restrict__ startT,
    const float* __restrict__ endT, float* __restrict__ out) {
  __shared__ __align__(16) unsigned short alds[NB * LROW];
  __shared__ float redz[NB], redg[NB];

  const int tid = threadIdx.x;
  const int wav = tid >> 6, lane = tid & 63;
  const int bl = lane & 15, h = lane >> 4;
  const int b0 = blockIdx.x * NB;

  if (wav == 0) {
    // A-frags: A[m=lane&15 -> j=16mt+bl][k=(lane>>4)*8+jj -> i] (R3-verified)
    short8 afrag[8][4];
#pragma unroll
    for (int mt = 0; mt < 8; ++mt) {
      const int j = mt * 16 + bl;
#pragma unroll
      for (int kc = 0; kc < 4; ++kc) {
        short8 a;
#pragma unroll
        for (int jj = 0; jj < 8; ++jj) {
          int i = kc * 32 + h * 8 + jj;
          a[jj] = (short)f2bf(__expf(trans[i * NUM_TAGS + j]) * 0.0078125f);
        }
        afrag[mt][kc] = a;
      }
    }

    const unsigned short* emb = em + (size_t)(b0 + bl) * TT * NUM_TAGS;

    // alpha_0[bl][j] = exp(start[j]) * em_exp[bl][0][j]; lane covers its
    // D-slots j = 16mt+4h+r  (all j covered across the 4 h-lanes per bl)
#pragma unroll
    for (int mt = 0; mt < 8; ++mt)
#pragma unroll
      for (int r = 0; r < 4; ++r) {
        int j = 16 * mt + 4 * h + r;
        alds[bl * LROW + j] = f2bf(__expf(startT[j]) * bf2f(emb[j]));
      }

    uint2 evb[8];
#pragma unroll
    for (int mt = 0; mt < 8; ++mt)
      evb[mt] = *(const uint2*)&emb[(size_t)1 * NUM_TAGS + 16 * mt + 4 * h];

    for (int t = 1; t < TT; ++t) {
      short8 bfrag[4];
#pragma unroll
      for (int kc = 0; kc < 4; ++kc)
        bfrag[kc] = *(const short8*)&alds[bl * LROW + kc * 32 + h * 8];

      float4v acc[8];
#pragma unroll
      for (int mt = 0; mt < 8; ++mt) acc[mt] = (float4v){0.f, 0.f, 0.f, 0.f};
#pragma unroll
      for (int kc = 0; kc < 4; ++kc)
#pragma unroll
        for (int mt = 0; mt < 8; ++mt)
          acc[mt] = __builtin_amdgcn_mfma_f32_16x16x32_bf16(
              afrag[mt][kc], bfrag[kc], acc[mt], 0, 0, 0);

      uint2 evn[8];
      if (t + 1 < TT) {
#pragma unroll
        for (int mt = 0; mt < 8; ++mt)
          evn[mt] = *(const uint2*)&emb[(size_t)(t + 1) * NUM_TAGS + 16 * mt + 4 * h];
      }

#pragma unroll
      for (int mt = 0; mt < 8; ++mt) {
        float e0 = __uint_as_float(evb[mt].x << 16);
        float e1 = __uint_as_float(evb[mt].x & 0xFFFF0000u);
        float e2 = __uint_as_float(evb[mt].y << 16);
        float e3 = __uint_as_float(evb[mt].y & 0xFFFF0000u);
        unsigned a0 = __float_as_uint(acc[mt][0] * e0) + 0x8000u;
        unsigned a1 = __float_as_uint(acc[mt][1] * e1) + 0x8000u;
        unsigned a2 = __float_as_uint(acc[mt][2] * e2) + 0x8000u;
        unsigned a3 = __float_as_uint(acc[mt][3] * e3) + 0x8000u;
        uint2 o;
        o.x = __builtin_amdgcn_perm(a1, a0, 0x07060302u);
        o.y = __builtin_amdgcn_perm(a3, a2, 0x07060302u);
        *(uint2*)&alds[bl * LROW + 16 * mt + 4 * h] = o;
      }
#pragma unroll
      for (int mt = 0; mt < 8; ++mt) evb[mt] = evn[mt];
    }

    // logZ: 4 lanes per b, 32 j's each
    {
      const int bb = lane >> 2, q = lane & 3;
      float sum = 0.f;
      for (int j = 32 * q; j < 32 * q + 32; ++j)
        sum += bf2f(alds[bb * LROW + j]) * __expf(endT[j]);
      sum += __shfl_xor(sum, 1, 64);
      sum += __shfl_xor(sum, 2, 64);
      if (q == 0) redz[bb] = __logf(sum) + 511.0f * 7.0f * 0.69314718055994531f;
    }
  } else {
    // gold score: 4 lanes per b, 128 t's each (runs under recurrence shadow)
    const int bb = lane >> 2, seg = lane & 3;
    const int* tb = tags + (size_t)(b0 + bb) * TT;
    const unsigned short* emb = em + (size_t)(b0 + bb) * TT * NUM_TAGS;
    float g = 0.f;
    int tg = tb[seg * 128];
    for (int t = seg * 128; t < seg * 128 + 128; ++t) {
      g += __logf(bf2f(emb[(size_t)t * NUM_TAGS + tg]));
      if (t < TT - 1) {
        int tn = tb[t + 1];
        g += trans[tg * NUM_TAGS + tn];
        tg = tn;
      }
    }
    if (seg == 0) g += startT[tb[0]];
    if (seg == 3) g += endT[tb[TT - 1]];
    g += __shfl_xor(g, 1, 64);
    g += __shfl_xor(g, 2, 64);
    if (seg == 0) redg[bb] = g;
  }

  __syncthreads();
  if (tid < NB) out[b0 + tid] = redz[tid] - redg[tid];
}

extern "C" void kernel_launch(void* const* d_in, const int* in_sizes, int n_in,
                              void* d_out, int out_size, void* d_ws, size_t ws_size,
                              hipStream_t stream) {
  const int* feats = (const int*)d_in[0];
  const int* tags = (const int*)d_in[1];
  const float* sw = (const float*)d_in[2];
  const float* trans = (const float*)d_in[3];
  const float* startT = (const float*)d_in[4];
  const float* endT = (const float*)d_in[5];
  float* out = (float*)d_out;

  if (ws_size >= NEED_FULL) {
    unsigned short* swT = (unsigned short*)d_ws;
    unsigned short* em = (unsigned short*)((char*)d_ws + SWT_BYTES);
    transpose_kernel<<<NUM_FEATS / 32, 256, 0, stream>>>(sw, swT);
    gather_kernel<<<BB * TT / 4, 256, 0, stream>>>(feats, swT, em);
    fwd_kernel<<<BB / NB, 128, 0, stream>>>(em, tags, trans, startT, endT, out);
  } else {
    unsigned short* em = (unsigned short*)d_ws;
    gather_f_kernel<<<BB * TT / 4, 256, 0, stream>>>(feats, sw, em);
    fwd_kernel<<<BB / NB, 128, 0, stream>>>(em, tags, trans, startT, endT, out);
  }
}

// Round 5
// 578.287 us; speedup vs baseline: 1.2313x; 1.2313x over previous
//
#include <hip/hip_runtime.h>

#define NUM_TAGS 128
#define NUM_FEATS 500000
#define BB 64
#define TT 512
#define FF 8

#define SWT_BYTES 128000000ull                 // 500000*128*2 (bf16)
#define EM_BYTES  (64ull * 512 * 128 * 2)      // 8 MB bf16
#define GEP_BYTES (4096ull * 4)                // gold emission partials
#define GTR_BYTES (64ull * 4)                  // gold transition part
#define NEED_FULL (SWT_BYTES + EM_BYTES + GEP_BYTES + GTR_BYTES)

typedef __attribute__((ext_vector_type(8))) short short8;
typedef __attribute__((ext_vector_type(4))) float float4v;

__device__ inline unsigned short f2bf(float f) {
  unsigned u = __float_as_uint(f);
  return (unsigned short)((u + 0x7fffu + ((u >> 16) & 1u)) >> 16);
}
__device__ inline float bf2f(unsigned short h) {
  return __uint_as_float(((unsigned)h) << 16);
}

// G0: gold transition+start+end score per batch (independent of emissions;
// runs first, off the critical path).
__global__ __launch_bounds__(256) void gold_trans_kernel(
    const int* __restrict__ tags, const float* __restrict__ trans,
    const float* __restrict__ startT, const float* __restrict__ endT,
    float* __restrict__ gold_tr) {
  const int b = blockIdx.x;
  const int* tb = tags + (size_t)b * TT;
  float g = 0.f;
  for (int t = threadIdx.x; t < TT - 1; t += 256)
    g += trans[tb[t] * NUM_TAGS + tb[t + 1]];
  if (threadIdx.x == 0) g += startT[tb[0]] + endT[tb[TT - 1]];
#pragma unroll
  for (int m = 32; m > 0; m >>= 1) g += __shfl_xor(g, m, 64);
  __shared__ float r[4];
  if ((threadIdx.x & 63) == 0) r[threadIdx.x >> 6] = g;
  __syncthreads();
  if (threadIdx.x == 0) gold_tr[b] = r[0] + r[1] + r[2] + r[3];
}

// T1: transpose sw [128][500000] fp32 -> swT [500000][128] bf16.
// 128x128 tiles: 512B-contiguous row segments on read, 256B rows on write.
__global__ __launch_bounds__(256) void transpose_kernel(
    const float* __restrict__ sw, unsigned short* __restrict__ swT) {
#define TS 136
  __shared__ unsigned short tile[128 * TS];
  const int f0 = blockIdx.x * 128;
  const int t = threadIdx.x;
  const int c = t & 31, kr = t >> 5;     // c: float4 col, kr: row 0..7
#pragma unroll
  for (int p = 0; p < 16; ++p) {
    int k = kr + 8 * p;
    int f = f0 + 4 * c;
    if (f < NUM_FEATS) {
      float4 v = *(const float4*)&sw[(size_t)k * NUM_FEATS + f];
      uint2 o;
      o.x = (unsigned)f2bf(v.x) | ((unsigned)f2bf(v.y) << 16);
      o.y = (unsigned)f2bf(v.z) | ((unsigned)f2bf(v.w) << 16);
      *(uint2*)&tile[k * TS + 4 * c] = o;
    }
  }
  __syncthreads();
  const int c2 = t & 31, fr = t >> 5;    // c2: uint2 col (4 k), fr: f 0..7
#pragma unroll
  for (int p = 0; p < 16; ++p) {
    int f = fr + 8 * p;
    if (f0 + f < NUM_FEATS) {
      uint2 o;
      o.x = (unsigned)tile[(4 * c2 + 0) * TS + f] |
            ((unsigned)tile[(4 * c2 + 1) * TS + f] << 16);
      o.y = (unsigned)tile[(4 * c2 + 2) * TS + f] |
            ((unsigned)tile[(4 * c2 + 3) * TS + f] << 16);
      *(uint2*)&swT[(size_t)(f0 + f) * NUM_TAGS + 4 * c2] = o;
    }
  }
#undef TS
}

// K1: 8 tokens/block (8 waves). Lane loads uint (2 bf16) per feature ->
// 256B/row wave-instruction. exp folded, em bf16. Gold-emission partial
// (em log-sum at the gold tag) reduced per block -> gold_ep[block].
__global__ __launch_bounds__(512) void gather_kernel(
    const int* __restrict__ feats, const unsigned short* __restrict__ swT,
    unsigned short* __restrict__ em, const int* __restrict__ tags,
    float* __restrict__ gold_ep) {
  const int w = threadIdx.x >> 6, lane = threadIdx.x & 63;
  const int token = blockIdx.x * 8 + w;
  const int* f = feats + (size_t)token * FF;
  float s0 = 0.f, s1 = 0.f;
#pragma unroll
  for (int i = 0; i < FF; ++i) {
    unsigned u = *(const unsigned*)&swT[(size_t)f[i] * NUM_TAGS + 2 * lane];
    s0 += __uint_as_float(u << 16);
    s1 += __uint_as_float(u & 0xFFFF0000u);
  }
  unsigned lo = f2bf(__expf(s0));
  unsigned hi = f2bf(__expf(s1));
  *(unsigned*)&em[(size_t)token * NUM_TAGS + 2 * lane] = lo | (hi << 16);

  int tg = tags[token];
  float c = (2 * lane == tg) ? s0 : ((2 * lane + 1 == tg) ? s1 : 0.f);
#pragma unroll
  for (int m = 32; m > 0; m >>= 1) c += __shfl_xor(c, m, 64);
  __shared__ float part[8];
  if (lane == 0) part[w] = c;
  __syncthreads();
  if (threadIdx.x == 0) {
    float s = 0.f;
#pragma unroll
    for (int i = 0; i < 8; ++i) s += part[i];
    gold_ep[blockIdx.x] = s;   // block b*64+i holds batch b's i-th partial
  }
}

// K1b fallback: strided fp32 gather (no transpose).
__global__ __launch_bounds__(512) void gather_f_kernel(
    const int* __restrict__ feats, const float* __restrict__ sw,
    unsigned short* __restrict__ em, const int* __restrict__ tags,
    float* __restrict__ gold_ep) {
  const int w = threadIdx.x >> 6, lane = threadIdx.x & 63;
  const int token = blockIdx.x * 8 + w;
  const int* f = feats + (size_t)token * FF;
  float s0 = 0.f, s1 = 0.f;
#pragma unroll
  for (int i = 0; i < FF; ++i) {
    s0 += sw[(size_t)(2 * lane) * NUM_FEATS + f[i]];
    s1 += sw[(size_t)(2 * lane + 1) * NUM_FEATS + f[i]];
  }
  unsigned lo = f2bf(__expf(s0));
  unsigned hi = f2bf(__expf(s1));
  *(unsigned*)&em[(size_t)token * NUM_TAGS + 2 * lane] = lo | (hi << 16);

  int tg = tags[token];
  float c = (2 * lane == tg) ? s0 : ((2 * lane + 1 == tg) ? s1 : 0.f);
#pragma unroll
  for (int m = 32; m > 0; m >>= 1) c += __shfl_xor(c, m, 64);
  __shared__ float part[8];
  if (lane == 0) part[w] = c;
  __syncthreads();
  if (threadIdx.x == 0) {
    float s = 0.f;
#pragma unroll
    for (int i = 0; i < 8; ++i) s += part[i];
    gold_ep[blockIdx.x] = s;
  }
}

// K2: MFMA forward, 16 batches/block, 4 waves j-split (2 j-tiles each ->
// 8 MFMA/wave/step, issue ~150cyc/SIMD). ev prefetched at TOP of step
// (~350cyc slack -> barrier vmcnt drain ~free, em is L2-resident bf16).
// Ping-pong alpha in LDS, 1 barrier/step. Gold comes in as partials.
#define NB 16
#define LROW 136   // shorts; 272B rows, 16B-aligned for b128

__global__ __launch_bounds__(256, 1) void fwd_kernel(
    const unsigned short* __restrict__ em, const float* __restrict__ trans,
    const float* __restrict__ startT, const float* __restrict__ endT,
    const float* __restrict__ gold_tr, const float* __restrict__ gold_ep,
    float* __restrict__ out) {
  __shared__ __align__(16) unsigned short alds[2][NB * LROW];
  __shared__ float red[16][17];
  __shared__ float redz[16];

  const int tid = threadIdx.x;
  const int w = tid >> 6, lane = tid & 63;
  const int bl = lane & 15, h = lane >> 4;
  const int b0 = blockIdx.x * NB;

  // A-frags for j-tiles 2w, 2w+1: A[m=bl -> j][k=h*8+jj -> i], *2^-7 folded
  short8 afrag[2][4];
#pragma unroll
  for (int mt = 0; mt < 2; ++mt) {
    const int j = (2 * w + mt) * 16 + bl;
#pragma unroll
    for (int kc = 0; kc < 4; ++kc) {
      short8 a;
#pragma unroll
      for (int jj = 0; jj < 8; ++jj) {
        int i = kc * 32 + h * 8 + jj;
        a[jj] = (short)f2bf(__expf(trans[i * NUM_TAGS + j]) * 0.0078125f);
      }
      afrag[mt][kc] = a;
    }
  }

  const unsigned short* emb = em + (size_t)(b0 + bl) * TT * NUM_TAGS;

  // alpha_0: thread (bl2=tid&15, jc=tid>>4) covers 8 j's
  {
    const int bl2 = tid & 15, jc = tid >> 4;
    const unsigned short* e2 = em + (size_t)(b0 + bl2) * TT * NUM_TAGS;
#pragma unroll
    for (int jj = 0; jj < 8; ++jj) {
      int j = jc * 8 + jj;
      alds[0][bl2 * LROW + j] = f2bf(__expf(startT[j]) * bf2f(e2[j]));
    }
  }
  __syncthreads();

  uint2 ev[2];
#pragma unroll
  for (int mt = 0; mt < 2; ++mt)
    ev[mt] = *(const uint2*)&emb[(size_t)NUM_TAGS + (2 * w + mt) * 16 + 4 * h];

  for (int t = 1; t < TT; ++t) {
    // prefetch next step's emissions FIRST (max slack before the barrier)
    uint2 evn[2];
    if (t + 1 < TT) {
#pragma unroll
      for (int mt = 0; mt < 2; ++mt)
        evn[mt] = *(const uint2*)&emb[(size_t)(t + 1) * NUM_TAGS +
                                      (2 * w + mt) * 16 + 4 * h];
    }

    const unsigned short* cur = alds[(t - 1) & 1];
    unsigned short* nxt = alds[t & 1];

    short8 bfrag[4];
#pragma unroll
    for (int kc = 0; kc < 4; ++kc)
      bfrag[kc] = *(const short8*)&cur[bl * LROW + kc * 32 + h * 8];

    float4v acc0 = {0.f, 0.f, 0.f, 0.f}, acc1 = {0.f, 0.f, 0.f, 0.f};
#pragma unroll
    for (int kc = 0; kc < 4; ++kc) {
      acc0 = __builtin_amdgcn_mfma_f32_16x16x32_bf16(afrag[0][kc], bfrag[kc], acc0, 0, 0, 0);
      acc1 = __builtin_amdgcn_mfma_f32_16x16x32_bf16(afrag[1][kc], bfrag[kc], acc1, 0, 0, 0);
    }

#pragma unroll
    for (int mt = 0; mt < 2; ++mt) {
      const float4v& A = mt ? acc1 : acc0;
      float e0 = __uint_as_float(ev[mt].x << 16);
      float e1 = __uint_as_float(ev[mt].x & 0xFFFF0000u);
      float e2 = __uint_as_float(ev[mt].y << 16);
      float e3 = __uint_as_float(ev[mt].y & 0xFFFF0000u);
      unsigned a0 = __float_as_uint(A[0] * e0) + 0x8000u;
      unsigned a1 = __float_as_uint(A[1] * e1) + 0x8000u;
      unsigned a2 = __float_as_uint(A[2] * e2) + 0x8000u;
      unsigned a3 = __float_as_uint(A[3] * e3) + 0x8000u;
      uint2 o;
      o.x = __builtin_amdgcn_perm(a1, a0, 0x07060302u);
      o.y = __builtin_amdgcn_perm(a3, a2, 0x07060302u);
      *(uint2*)&nxt[bl * LROW + (2 * w + mt) * 16 + 4 * h] = o;
    }
    ev[0] = evn[0];
    ev[1] = evn[1];
    __syncthreads();
  }

  // logZ partials: alpha_511 is in alds[1]
  {
    const int bl2 = tid & 15, jc = tid >> 4;
    float s = 0.f;
#pragma unroll
    for (int jj = 0; jj < 8; ++jj) {
      int j = jc * 8 + jj;
      s += bf2f(alds[1][bl2 * LROW + j]) * __expf(endT[j]);
    }
    red[jc][bl2] = s;
  }
  __syncthreads();
  if (tid < 16) {
    float s = 0.f;
#pragma unroll
    for (int q = 0; q < 16; ++q) s += red[q][tid];
    redz[tid] = __logf(s) + 511.0f * 7.0f * 0.69314718055994531f;
  }
  __syncthreads();

  // gold emission partials: 64 per batch; thread (bl2, q) sums 4
  {
    const int bl2 = tid & 15, q = tid >> 4;
    const float* gp = gold_ep + (size_t)(b0 + bl2) * 64 + q * 4;
    red[q][bl2] = gp[0] + gp[1] + gp[2] + gp[3];
  }
  __syncthreads();
  if (tid < 16) {
    float g = gold_tr[b0 + tid];
#pragma unroll
    for (int q = 0; q < 16; ++q) g += red[q][tid];
    out[b0 + tid] = redz[tid] - g;
  }
}

extern "C" void kernel_launch(void* const* d_in, const int* in_sizes, int n_in,
                              void* d_out, int out_size, void* d_ws, size_t ws_size,
                              hipStream_t stream) {
  const int* feats = (const int*)d_in[0];
  const int* tags = (const int*)d_in[1];
  const float* sw = (const float*)d_in[2];
  const float* trans = (const float*)d_in[3];
  const float* startT = (const float*)d_in[4];
  const float* endT = (const float*)d_in[5];
  float* out = (float*)d_out;

  if (ws_size >= NEED_FULL) {
    unsigned short* swT = (unsigned short*)d_ws;
    unsigned short* em = (unsigned short*)((char*)d_ws + SWT_BYTES);
    float* gold_ep = (float*)((char*)d_ws + SWT_BYTES + EM_BYTES);
    float* gold_tr = (float*)((char*)d_ws + SWT_BYTES + EM_BYTES + GEP_BYTES);
    gold_trans_kernel<<<BB, 256, 0, stream>>>(tags, trans, startT, endT, gold_tr);
    transpose_kernel<<<(NUM_FEATS + 127) / 128, 256, 0, stream>>>(sw, swT);
    gather_kernel<<<BB * TT / 8, 512, 0, stream>>>(feats, swT, em, tags, gold_ep);
    fwd_kernel<<<BB / NB, 256, 0, stream>>>(em, trans, startT, endT, gold_tr, gold_ep, out);
  } else {
    unsigned short* em = (unsigned short*)d_ws;
    float* gold_ep = (float*)((char*)d_ws + EM_BYTES);
    float* gold_tr = (float*)((char*)d_ws + EM_BYTES + GEP_BYTES);
    gold_trans_kernel<<<BB, 256, 0, stream>>>(tags, trans, startT, endT, gold_tr);
    gather_f_kernel<<<BB * TT / 8, 512, 0, stream>>>(feats, sw, em, tags, gold_ep);
    fwd_kernel<<<BB / NB, 256, 0, stream>>>(em, trans, startT, endT, gold_tr, gold_ep, out);
  }
}